// Round 1
// baseline (80.456 us; speedup 1.0000x reference)
//
#include <hip/hip_runtime.h>

// ConvCNP encoder: out[b,c,j,i] = FM[b, g=i*128+j, c],
//   FM[...,0] = sum_n exp(-0.5*||grid_g - X_bn||^2)            (density)
//   FM[...,c] = (sum_n w_n * Y_bn[c-1]) / density, c=1,2
// B=4, N_CTX=1024, grid = 128x128 meshgrid('ij') of linspace(-2,2,128).

#define N_CTX 1024
#define G_PER_B 16384   // 128*128

__device__ __forceinline__ float fast_exp2(float x) {
#if __has_builtin(__builtin_amdgcn_exp2f)
  return __builtin_amdgcn_exp2f(x);
#else
  return exp2f(x);
#endif
}

__global__ __launch_bounds__(256) void convcnp_encoder_kernel(
    const float* __restrict__ X,     // [B, N_CTX, 2]
    const float* __restrict__ Y,     // [B, N_CTX, 2]
    const float* __restrict__ grid,  // [G_PER_B, 2]
    float* __restrict__ out)         // [B, 3, 128, 128]
{
  __shared__ float4 s[N_CTX];        // (x0, x1, y0, y1) per context point

  const int t   = threadIdx.x;
  const int gid = blockIdx.x * 256 + t;
  const int b   = gid >> 14;         // 16384 outputs per batch; 256 | 16384 so
                                     // every thread in a block shares b
  const int p   = gid & (G_PER_B - 1); // p = j*128 + i  (output-flat order)
  const int j   = p >> 7;
  const int i   = p & 127;
  const int g   = i * 128 + j;       // grid index: grid[g] = (gx[i], gy[j])

  // Stage this batch's X/Y into LDS (coalesced float2 loads, 4 per thread).
  const float2* Xb = (const float2*)(X + b * (N_CTX * 2));
  const float2* Yb = (const float2*)(Y + b * (N_CTX * 2));
#pragma unroll
  for (int n = t; n < N_CTX; n += 256) {
    float2 x = Xb[n];
    float2 y = Yb[n];
    s[n] = make_float4(x.x, x.y, y.x, y.y);
  }
  __syncthreads();

  const float gx = grid[2 * g];
  const float gy = grid[2 * g + 1];

  // exp(-0.5*d2) = 2^(d2 * (-0.5*log2(e)))
  const float C = -0.72134752044448170f;

  float acc0 = 0.f, acc1 = 0.f, acc2 = 0.f;
#pragma unroll 8
  for (int n = 0; n < N_CTX; ++n) {
    float4 v = s[n];                 // broadcast LDS read (all lanes same addr)
    float dx = gx - v.x;
    float dy = gy - v.y;
    float d2 = __builtin_fmaf(dy, dy, dx * dx);
    float w  = fast_exp2(d2 * C);
    acc0 += w;
    acc1 = __builtin_fmaf(w, v.z, acc1);
    acc2 = __builtin_fmaf(w, v.w, acc2);
  }

  const int base = b * (3 * G_PER_B) + p;   // consecutive threads -> coalesced
  out[base]                = acc0;
  out[base + G_PER_B]      = acc1 / acc0;
  out[base + 2 * G_PER_B]  = acc2 / acc0;
}

extern "C" void kernel_launch(void* const* d_in, const int* in_sizes, int n_in,
                              void* d_out, int out_size, void* d_ws, size_t ws_size,
                              hipStream_t stream) {
  const float* X    = (const float*)d_in[0];
  const float* Y    = (const float*)d_in[1];
  const float* grid = (const float*)d_in[2];
  float* out        = (float*)d_out;

  // 4 batches * 16384 grid points = 65536 threads = 256 blocks of 256
  convcnp_encoder_kernel<<<dim3(256), dim3(256), 0, stream>>>(X, Y, grid, out);
}

// Round 2
// 73.675 us; speedup vs baseline: 1.0920x; 1.0920x over previous
//
#include <hip/hip_runtime.h>

// ConvCNP encoder: out[b,c,j,i] = FM[b, g=i*128+j, c],
//   FM[...,0] = sum_n exp(-0.5*||grid_g - X_bn||^2)            (density)
//   FM[...,c] = (sum_n w_n * Y_bn[c-1]) / density, c=1,2
// B=4, N_CTX=1024, grid = 128x128 meshgrid('ij') of linspace(-2,2,128).
//
// R1: split the N-reduction across 4 waves per output group to get
// 4 blocks/CU (16 waves/CU) instead of 1 wave/SIMD — R0 was latency-bound
// (190 cyc/iter ~= exposed ds_read latency with no TLP).

#define N_CTX   1024
#define G_PER_B 16384   // 128*128
#define NQ      4       // N-chunks (one per wave)
#define OPB     64      // outputs per block
#define CHUNK   (N_CTX / NQ)   // 256

__device__ __forceinline__ float fast_exp2(float x) {
#if __has_builtin(__builtin_amdgcn_exp2f)
  return __builtin_amdgcn_exp2f(x);
#else
  return exp2f(x);
#endif
}

__global__ __launch_bounds__(256) void convcnp_encoder_kernel(
    const float* __restrict__ X,     // [B, N_CTX, 2]
    const float* __restrict__ Y,     // [B, N_CTX, 2]
    const float* __restrict__ grid,  // [G_PER_B, 2]
    float* __restrict__ out)         // [B, 3, 128, 128]
{
  __shared__ float4 s[N_CTX];            // (x0*SC, x1*SC, y0, y1)
  __shared__ float  red[NQ][OPB][3];     // cross-wave partials

  const int t  = threadIdx.x;
  const int o  = t & (OPB - 1);          // output slot within block
  const int q  = t >> 6;                 // wave index = N-chunk index

  const int pg = blockIdx.x * OPB + o;   // global output index
  const int b  = pg >> 14;               // 256 blocks per batch -> uniform b
  const int p  = pg & (G_PER_B - 1);     // p = j*128 + i (output-flat order)
  const int j  = p >> 7;
  const int i  = p & 127;
  const int g  = i * 128 + j;            // grid[g] = (gx[i], gy[j])

  // SC = sqrt(0.5 * log2(e)); pre-scaling X lets the inner loop compute
  // w = exp2(-(dx'^2 + dy'^2)) with the negation folded into v_exp_f32.
  const float SC = 0.84932180028801907f;

  // Stage this batch's X/Y into LDS (coalesced float2 loads, 4 per thread).
  const float2* Xb = (const float2*)(X + b * (N_CTX * 2));
  const float2* Yb = (const float2*)(Y + b * (N_CTX * 2));
#pragma unroll
  for (int n = t; n < N_CTX; n += 256) {
    float2 x = Xb[n];
    float2 y = Yb[n];
    s[n] = make_float4(x.x * SC, x.y * SC, y.x, y.y);
  }
  __syncthreads();

  const float gxs = grid[2 * g] * SC;
  const float gys = grid[2 * g + 1] * SC;

  float acc0 = 0.f, acc1 = 0.f, acc2 = 0.f;
  const int n0 = q * CHUNK;
#pragma unroll 8
  for (int n = n0; n < n0 + CHUNK; ++n) {
    float4 v = s[n];                 // broadcast LDS read (all lanes same addr)
    float dx = gxs - v.x;
    float dy = gys - v.y;
    float d2 = __builtin_fmaf(dy, dy, dx * dx);
    float w  = fast_exp2(-d2);
    acc0 += w;
    acc1 = __builtin_fmaf(w, v.z, acc1);
    acc2 = __builtin_fmaf(w, v.w, acc2);
  }

  red[q][o][0] = acc0;
  red[q][o][1] = acc1;
  red[q][o][2] = acc2;
  __syncthreads();

  if (t < OPB) {
    float a0 = 0.f, a1 = 0.f, a2 = 0.f;
#pragma unroll
    for (int qq = 0; qq < NQ; ++qq) {
      a0 += red[qq][t][0];
      a1 += red[qq][t][1];
      a2 += red[qq][t][2];
    }
    const int base = b * (3 * G_PER_B) + p;  // lanes -> consecutive p: coalesced
    out[base]               = a0;
    out[base + G_PER_B]     = a1 / a0;
    out[base + 2 * G_PER_B] = a2 / a0;
  }
}

extern "C" void kernel_launch(void* const* d_in, const int* in_sizes, int n_in,
                              void* d_out, int out_size, void* d_ws, size_t ws_size,
                              hipStream_t stream) {
  const float* X    = (const float*)d_in[0];
  const float* Y    = (const float*)d_in[1];
  const float* grid = (const float*)d_in[2];
  float* out        = (float*)d_out;

  // 65536 outputs / 64 per block = 1024 blocks -> 4 blocks/CU, 16 waves/CU.
  convcnp_encoder_kernel<<<dim3(1024), dim3(256), 0, stream>>>(X, Y, grid, out);
}

// Round 3
// 68.288 us; speedup vs baseline: 1.1782x; 1.0789x over previous
//
#include <hip/hip_runtime.h>

// ConvCNP encoder: out[b,c,jy,ix] = FM[b, g=ix*128+jy, c]
//   density = sum_n exp(-0.5*||grid_g - X_bn||^2); ch1,2 = weighted Y / density
// B=4, N_CTX=1024, grid = meshgrid('ij') of linspace(-2,2,128).
//
// R2: per-CU cost was ~45 cyc per wave ds_read_b128 regardless of occupancy
// (R0 vs R1) -> amortize LDS reads 16x: each thread owns a 4(ix)x4(jy) output
// tile and uses the separable Gaussian w = Ex(ix)*Ey(jy): 8 exps + 48 FMAs
// per context point per thread. N split into 32 chunks for TLP (8 waves/CU),
// combined with a 5-level LDS tree.

#define N_CTX   1024
#define G_PER_B 16384
#define NQ      32            // N-chunks
#define CHUNK   (N_CTX / NQ)  // 32
#define TPB     8             // tiles per block (256 thr = 8 tiles x 32 chunks)

typedef float fv4 __attribute__((ext_vector_type(4)));

__device__ __forceinline__ float fast_exp2(float x) {
#if __has_builtin(__builtin_amdgcn_exp2f)
  return __builtin_amdgcn_exp2f(x);
#else
  return exp2f(x);
#endif
}

__global__ __launch_bounds__(256) void convcnp_encoder_kernel(
    const float* __restrict__ X,     // [B, N_CTX, 2]
    const float* __restrict__ Y,     // [B, N_CTX, 2]
    const float* __restrict__ grid,  // [G_PER_B, 2]
    float* __restrict__ out)         // [B, 3, 128, 128]
{
  // ctx staged with +16B pad every 32 entries so the 8 distinct chunk
  // addresses inside a wave hit disjoint bank quads (stride 33*16B).
  __shared__ float4 s[N_CTX + (N_CTX / 32)];      // 1056 entries
  __shared__ fv4 red[16][TPB][13];                // 13 (not 12): bank-spread pad

  const int t    = threadIdx.x;
  const int tile = t & 7;        // tile slot in block
  const int q    = t >> 3;       // N-chunk index, 0..31

  const int tau = blockIdx.x * TPB + tile;  // global tile id, 0..4095
  const int b   = tau >> 10;                // uniform per block (1024 % 8 == 0)
  const int rem = tau & 1023;
  const int ixt = rem & 31;                 // tile's ix group (4 ix each)
  const int jyt = rem >> 5;                 // tile's jy group (uniform per block)

  // SC = sqrt(0.5*log2(e)): w = exp2(-(dx')^2) * exp2(-(dy')^2)
  const float SC = 0.84932180028801907f;

  // ---- stage this batch's context points into LDS (coalesced) ----
  const float2* Xb = (const float2*)(X + b * (N_CTX * 2));
  const float2* Yb = (const float2*)(Y + b * (N_CTX * 2));
#pragma unroll
  for (int k = 0; k < 4; ++k) {
    int n = t + 256 * k;
    float2 x = Xb[n];
    float2 y = Yb[n];
    s[n + (n >> 5)] = make_float4(x.x * SC, x.y * SC, y.x, y.y);
  }

  // ---- per-thread grid coords (one-time scattered loads, L2-cached) ----
  fv4 gxs;
#pragma unroll
  for (int a = 0; a < 4; ++a)
    gxs[a] = grid[(4 * ixt + a) * 256] * SC;    // gx[ix] = grid[2*(ix*128)]
  float gys[4];
#pragma unroll
  for (int bb = 0; bb < 4; ++bb)
    gys[bb] = grid[2 * (4 * jyt + bb) + 1] * SC; // gy[jy] = grid[2*jy+1]

  __syncthreads();

  fv4 acc0[4], acc1[4], acc2[4];   // [jy-sub], components = ix-sub
#pragma unroll
  for (int bb = 0; bb < 4; ++bb) {
    acc0[bb] = (fv4){0.f, 0.f, 0.f, 0.f};
    acc1[bb] = (fv4){0.f, 0.f, 0.f, 0.f};
    acc2[bb] = (fv4){0.f, 0.f, 0.f, 0.f};
  }

  // ---- main loop: 32 ctx points for this chunk ----
  const float4* sp = &s[q * 33];   // 32 entries + pad -> linear inner index
#pragma unroll 4
  for (int it = 0; it < CHUNK; ++it) {
    float4 v = sp[it];             // (x0*SC, x1*SC, y0, y1)
    fv4 dx = gxs - v.x;
    fv4 ex;
#pragma unroll
    for (int a = 0; a < 4; ++a) ex[a] = fast_exp2(-(dx[a] * dx[a]));
    float ey[4], ey0[4], ey1[4];
#pragma unroll
    for (int bb = 0; bb < 4; ++bb) {
      float dy = gys[bb] - v.y;
      float e  = fast_exp2(-(dy * dy));
      ey[bb]  = e;
      ey0[bb] = e * v.z;
      ey1[bb] = e * v.w;
    }
#pragma unroll
    for (int bb = 0; bb < 4; ++bb) {
      acc0[bb] += ex * ey[bb];     // 4 fma each (vector * splat + add)
      acc1[bb] += ex * ey0[bb];
      acc2[bb] += ex * ey1[bb];
    }
  }

  // ---- 5-level cross-chunk tree reduction (32 -> 1) in LDS ----
#pragma unroll
  for (int step = 16; step >= 1; step >>= 1) {
    if (q >= step && q < 2 * step) {
      fv4* d = &red[q - step][tile][0];
#pragma unroll
      for (int bb = 0; bb < 4; ++bb) {
        d[bb] = acc0[bb]; d[4 + bb] = acc1[bb]; d[8 + bb] = acc2[bb];
      }
    }
    __syncthreads();
    if (q < step) {
      fv4* r = &red[q][tile][0];
#pragma unroll
      for (int bb = 0; bb < 4; ++bb) {
        acc0[bb] += r[bb]; acc1[bb] += r[4 + bb]; acc2[bb] += r[8 + bb];
      }
    }
    __syncthreads();
  }

  // ---- epilogue: q==0 threads hold final sums for their tile ----
  if (q == 0) {
    const int ob = b * (3 * G_PER_B) + jyt * 4 * 128 + ixt * 4;
#pragma unroll
    for (int bb = 0; bb < 4; ++bb) {
      fv4 d  = acc0[bb];
      fv4 o1 = acc1[bb] / d;
      fv4 o2 = acc2[bb] / d;
      const int row = ob + bb * 128;
      *(fv4*)(out + row)                = d;   // 16B aligned: ixt*4 floats
      *(fv4*)(out + row + G_PER_B)      = o1;
      *(fv4*)(out + row + 2 * G_PER_B)  = o2;
    }
  }
}

extern "C" void kernel_launch(void* const* d_in, const int* in_sizes, int n_in,
                              void* d_out, int out_size, void* d_ws, size_t ws_size,
                              hipStream_t stream) {
  const float* X    = (const float*)d_in[0];
  const float* Y    = (const float*)d_in[1];
  const float* grid = (const float*)d_in[2];
  float* out        = (float*)d_out;

  // 4096 tiles / 8 per block = 512 blocks (2/CU), 256 threads each.
  convcnp_encoder_kernel<<<dim3(512), dim3(256), 0, stream>>>(X, Y, grid, out);
}